// Round 5
// baseline (234.166 us; speedup 1.0000x reference)
//
#include <hip/hip_runtime.h>
#include <hip/hip_bf16.h>

// Problem constants: B=2, L=2048, D=1024, H=16, d_k=64
#define Hh 16
#define Ll 2048
#define Dd 1024
#define DK 64
#define Mm 4096  // B*L
#define Kk 1024
#define Nn 1024

typedef short bf16x8 __attribute__((ext_vector_type(8)));
typedef float f32x4 __attribute__((ext_vector_type(4)));

static __device__ __forceinline__ unsigned short f2bf(float f) {
    union { __hip_bfloat16 b; unsigned short u; } cv;
    cv.b = __float2bfloat16(f);
    return cv.u;
}

static __device__ __forceinline__ unsigned pack_bf2(float a, float b) {
    union { __hip_bfloat162 h; unsigned u; } cv;
    cv.h = __float22bfloat162_rn(make_float2(a, b));
    return cv.u;  // a low 16, b high 16
}

static __device__ __forceinline__ float fexp2(float x) {
    return __builtin_amdgcn_exp2f(x);  // single v_exp_f32
}

// async global->LDS, 16B/lane. LDS dest = wave-uniform base + lane*16 (HW rule).
static __device__ __forceinline__ void glds16(const ushort* g, ushort* l) {
    __builtin_amdgcn_global_load_lds((const __attribute__((address_space(1))) unsigned int*)g,
                                     (__attribute__((address_space(3))) unsigned int*)l,
                                     16, 0, 0);
}

// ---------------- fused fp32 -> bf16 casts ----------------
__global__ __launch_bounds__(256) void cast_all(
    const float* __restrict__ q, const float* __restrict__ k, const float* __restrict__ v,
    const float* __restrict__ wq, const float* __restrict__ wk, const float* __restrict__ wv,
    const float* __restrict__ wo,
    ushort* __restrict__ qb, ushort* __restrict__ kb, ushort* __restrict__ vb,
    ushort* __restrict__ wqb, ushort* __restrict__ wkb, ushort* __restrict__ wvb,
    ushort* __restrict__ wob) {
    const int bx = blockIdx.x;
    const float4* s; ushort4* d; int base;
    if      (bx <  4096) { s = (const float4*)q;  d = (ushort4*)qb;  base = 0; }
    else if (bx <  8192) { s = (const float4*)k;  d = (ushort4*)kb;  base = 4096; }
    else if (bx < 12288) { s = (const float4*)v;  d = (ushort4*)vb;  base = 8192; }
    else if (bx < 13312) { s = (const float4*)wq; d = (ushort4*)wqb; base = 12288; }
    else if (bx < 14336) { s = (const float4*)wk; d = (ushort4*)wkb; base = 13312; }
    else if (bx < 15360) { s = (const float4*)wv; d = (ushort4*)wvb; base = 14336; }
    else                 { s = (const float4*)wo; d = (ushort4*)wob; base = 15360; }
    const int i = (bx - base) * 256 + threadIdx.x;
    float4 vv = s[i];
    ushort4 o;
    o.x = f2bf(vv.x); o.y = f2bf(vv.y); o.z = f2bf(vv.z); o.w = f2bf(vv.w);
    d[i] = o;
}

// ---------------- fused QKV projection GEMM ----------------
// C = A @ W^T + bias. z=0: Q, pre-scaled by 0.125*log2(e), scatter to [BH,L,64].
// z=1: K, scatter to [BH,L,64]. z=2: V, LDS-transposed epilogue -> [BH,64,L].
__global__ __launch_bounds__(256) void gemm_qkv(
    const ushort* __restrict__ A0, const ushort* __restrict__ A1, const ushort* __restrict__ A2,
    const ushort* __restrict__ W0, const ushort* __restrict__ W1, const ushort* __restrict__ W2,
    const float* __restrict__ b0, const float* __restrict__ b1, const float* __restrict__ b2,
    ushort* __restrict__ O0, ushort* __restrict__ O1, ushort* __restrict__ OVt) {
    __shared__ __align__(16) ushort SM[2 * 128 * 32];  // As | Bs ; reused as T in z==2 epilogue
    ushort* As = SM;
    ushort* Bs = SM + 4096;
    const int z = blockIdx.z;
    const ushort* A = (z == 0) ? A0 : (z == 1) ? A1 : A2;
    const ushort* W = (z == 0) ? W0 : (z == 1) ? W1 : W2;
    const float* bias = (z == 0) ? b0 : (z == 1) ? b1 : b2;

    const int t = threadIdx.x;
    const int wave = t >> 6, lane = t & 63;
    const int quad = lane >> 4, l15 = lane & 15;
    const int brow = blockIdx.y * 128, bcol = blockIdx.x * 128;
    const int wr = (wave >> 1) * 64, wc = (wave & 1) * 64;
    const int gr = wave * 16 + (lane >> 2);
    const int gc = (lane & 3) * 8;

    f32x4 acc[4][4] = {};

    for (int k0 = 0; k0 < Kk; k0 += 32) {
        __syncthreads();
        glds16(A + (size_t)(brow + gr) * Kk + k0 + gc,      As + wave * 512);
        glds16(A + (size_t)(brow + 64 + gr) * Kk + k0 + gc, As + 2048 + wave * 512);
        glds16(W + (size_t)(bcol + gr) * Kk + k0 + gc,      Bs + wave * 512);
        glds16(W + (size_t)(bcol + 64 + gr) * Kk + k0 + gc, Bs + 2048 + wave * 512);
        __syncthreads();

        bf16x8 af[4], bfr[4];
#pragma unroll
        for (int i = 0; i < 4; i++)
            af[i] = *(const bf16x8*)(As + (wr + i * 16 + l15) * 32 + quad * 8);
#pragma unroll
        for (int j = 0; j < 4; j++)
            bfr[j] = *(const bf16x8*)(Bs + (wc + j * 16 + l15) * 32 + quad * 8);
#pragma unroll
        for (int i = 0; i < 4; i++)
#pragma unroll
            for (int j = 0; j < 4; j++)
                acc[i][j] = __builtin_amdgcn_mfma_f32_16x16x32_bf16(af[i], bfr[j], acc[i][j], 0, 0, 0);
    }

    // C/D layout: row = quad*4+r, col = l15
    if (z < 2) {
        ushort* Out = (z == 0) ? O0 : O1;
        const float oscl = (z == 0) ? 0.18033688f : 1.0f;  // 0.125*log2(e) folded into Q
#pragma unroll
        for (int i = 0; i < 4; i++)
#pragma unroll
            for (int j = 0; j < 4; j++) {
                const int n = bcol + wc + j * 16 + l15;
                const float bv = bias[n];
                const int h = n >> 6, dk = n & 63;
#pragma unroll
                for (int r = 0; r < 4; r++) {
                    const int m = brow + wr + i * 16 + quad * 4 + r;
                    const int b = m >> 11, l = m & 2047;
                    Out[((size_t)(b * Hh + h) * Ll + l) * DK + dk] = f2bf((acc[i][j][r] + bv) * oscl);
                }
            }
    } else {
        // LDS transpose epilogue: emit V^T [BH, 64, L] with coalesced 16B stores.
        ushort* T = SM;  // T[32][136]
        const int b = brow >> 11;
        const int lbase = brow & 2047;
        const int npr = (wave & 1) * 16 + l15;
#pragma unroll
        for (int j = 0; j < 4; j++) {
            __syncthreads();
            const float bv = bias[bcol + wc + j * 16 + l15];
#pragma unroll
            for (int i = 0; i < 4; i++)
#pragma unroll
                for (int r = 0; r < 4; r++) {
                    const int m = wr + i * 16 + quad * 4 + r;
                    T[npr * 136 + m] = f2bf(acc[i][j][r] + bv);
                }
            __syncthreads();
#pragma unroll
            for (int cc = 0; cc < 2; cc++) {
                const int idx = t + cc * 256;
                const int ni = idx >> 4;
                const int ms = idx & 15;
                const int n = bcol + (ni >> 4) * 64 + j * 16 + (ni & 15);
                const int hh = n >> 6, dk = n & 63;
                uint4 val = *(const uint4*)(T + ni * 136 + ms * 8);
                *(uint4*)(OVt + ((size_t)(b * Hh + hh) * DK + dk) * Ll + lbase + ms * 8) = val;
            }
        }
    }
}

// ---------------- fused attention ----------------
// Block = 2 waves x 32 q = 64 q-rows, one head; 1024 blocks = 4/CU.
// Wave 0 stages K (two d-panels [128][32]); wave 1 stages V ([64 d][swizzled keys]).
// Mask constant folded into MFMA acc init for wave-uniform tiles; single v_exp per score.
__global__ __launch_bounds__(128) void attn_kernel(const ushort* __restrict__ Q,
                                                   const ushort* __restrict__ Kp,
                                                   const ushort* __restrict__ Vt,
                                                   ushort* __restrict__ Oout,
                                                   const int* __restrict__ masksize) {
    __shared__ __align__(16) ushort Ks[2 * 128 * 32];  // 16KB
    __shared__ __align__(16) ushort Vs[64 * 128];      // 16KB
    const int t = threadIdx.x;
    const int wave = t >> 6, lane = t & 63;
    const int quad = lane >> 4, l15 = lane & 15;
    const int bx = blockIdx.x;
    const int bh = bx & 31, qc = bx >> 5;           // 32 q-chunks of 64
    const int q0w = qc * 64 + wave * 32;            // this wave's 32 q-rows
    const int half = masksize[0] >> 1;
    const unsigned wid = (unsigned)(2 * half);

    const ushort* Qb = Q + (size_t)bh * (Ll * DK);
    const ushort* Kb = Kp + (size_t)bh * (Ll * DK);
    const ushort* Vb = Vt + (size_t)bh * (DK * Ll);

    // Q fragments (B-operand of S^T MFMA), two 16-q groups A/B
    const bf16x8 qA0 = *(const bf16x8*)(Qb + (size_t)(q0w + l15) * DK + quad * 8);
    const bf16x8 qA1 = *(const bf16x8*)(Qb + (size_t)(q0w + l15) * DK + 32 + quad * 8);
    const bf16x8 qB0 = *(const bf16x8*)(Qb + (size_t)(q0w + 16 + l15) * DK + quad * 8);
    const bf16x8 qB1 = *(const bf16x8*)(Qb + (size_t)(q0w + 16 + l15) * DK + 32 + quad * 8);

    const float C2IN  = (1.0f - 24.0f) * 1.44269504088896f;
    const float C2OUT = -24.0f * 1.44269504088896f;
    const float E1 = 2.718281828f;  // ratio 2^(C2IN-C2OUT)

    f32x4 OA[4] = {}, OB[4] = {};
    float rsA = 0.f, rsB = 0.f;

    // staging geometry
    const int krow = lane >> 2;              // key within 16-key chunk (wave 0)
    const int kcol8 = (lane & 3) * 8;        // d offset within 32-d panel
    const int vdl = lane >> 4;               // d within 4-row group (wave 1)
    const int vg0 = 2 * (lane & 15);         // LDS granule-pair base

    for (int kt = 0; kt < Ll; kt += 128) {
        __syncthreads();  // both waves done reading previous tile
        if (wave == 0) {
#pragma unroll
            for (int c = 0; c < 8; c++)
#pragma unroll
                for (int pan = 0; pan < 2; pan++)
                    glds16(Kb + (size_t)(kt + c * 16 + krow) * DK + pan * 32 + kcol8,
                           Ks + (pan * 128 + c * 16) * 32);
        } else {
#pragma unroll
            for (int i = 0; i < 16; i++) {
                const int d = i * 4 + vdl;
                const int g0 = vg0 ^ (d & 30);
                glds16(Vb + (size_t)d * Ll + kt + g0 * 4, Vs + i * 512);
            }
        }
        __syncthreads();  // vmcnt(0) drain -> LDS ready

        // wave-uniform band-mask mode for this tile
        const int qlo = q0w, qhi = q0w + 31;
        const bool allout = (kt + 127 < qlo - half) || (kt > qhi + half);
        const bool allin  = (kt >= qhi - half) && (kt + 127 <= qlo + half);
        const bool uniform = allin || allout;
        const float cinit = allin ? C2IN : C2OUT;  // acc init (C2OUT for mixed)
        f32x4 cvec = {cinit, cinit, cinit, cinit};

#pragma unroll
        for (int s = 0; s < 4; s++) {
            const bf16x8 kf00 = *(const bf16x8*)(Ks + ((2 * s) * 16 + l15) * 32 + quad * 8);
            const bf16x8 kf01 = *(const bf16x8*)(Ks + 4096 + ((2 * s) * 16 + l15) * 32 + quad * 8);
            const bf16x8 kf10 = *(const bf16x8*)(Ks + ((2 * s + 1) * 16 + l15) * 32 + quad * 8);
            const bf16x8 kf11 = *(const bf16x8*)(Ks + 4096 + ((2 * s + 1) * 16 + l15) * 32 + quad * 8);
            f32x4 zA0 = __builtin_amdgcn_mfma_f32_16x16x32_bf16(kf00, qA0, cvec, 0, 0, 0);
            zA0 = __builtin_amdgcn_mfma_f32_16x16x32_bf16(kf01, qA1, zA0, 0, 0, 0);
            f32x4 zA1 = __builtin_amdgcn_mfma_f32_16x16x32_bf16(kf10, qA0, cvec, 0, 0, 0);
            zA1 = __builtin_amdgcn_mfma_f32_16x16x32_bf16(kf11, qA1, zA1, 0, 0, 0);
            f32x4 zB0 = __builtin_amdgcn_mfma_f32_16x16x32_bf16(kf00, qB0, cvec, 0, 0, 0);
            zB0 = __builtin_amdgcn_mfma_f32_16x16x32_bf16(kf01, qB1, zB0, 0, 0, 0);
            f32x4 zB1 = __builtin_amdgcn_mfma_f32_16x16x32_bf16(kf10, qB0, cvec, 0, 0, 0);
            zB1 = __builtin_amdgcn_mfma_f32_16x16x32_bf16(kf11, qB1, zB1, 0, 0, 0);

            float pA[8], pB[8];
            if (uniform) {
#pragma unroll
                for (int g = 0; g < 2; g++)
#pragma unroll
                    for (int r = 0; r < 4; r++) {
                        pA[g * 4 + r] = fexp2(g ? zA1[r] : zA0[r]);
                        pB[g * 4 + r] = fexp2(g ? zB1[r] : zB0[r]);
                    }
            } else {
                const int kb = kt + s * 32 + quad * 4 + half;
#pragma unroll
                for (int g = 0; g < 2; g++)
#pragma unroll
                    for (int r = 0; r < 4; r++) {
                        const unsigned ttA = (unsigned)(kb + g * 16 + r - (q0w + l15));
                        const unsigned ttB = (unsigned)(kb + g * 16 + r - (q0w + 16 + l15));
                        pA[g * 4 + r] = fexp2(g ? zA1[r] : zA0[r]) * (ttA <= wid ? E1 : 1.0f);
                        pB[g * 4 + r] = fexp2(g ? zB1[r] : zB0[r]) * (ttB <= wid ? E1 : 1.0f);
                    }
            }
            rsA += ((pA[0] + pA[1]) + (pA[2] + pA[3])) + ((pA[4] + pA[5]) + (pA[6] + pA[7]));
            rsB += ((pB[0] + pB[1]) + (pB[2] + pB[3])) + ((pB[4] + pB[5]) + (pB[6] + pB[7]));

            bf16x8 pfA, pfB;
            ((unsigned*)&pfA)[0] = pack_bf2(pA[0], pA[1]);
            ((unsigned*)&pfA)[1] = pack_bf2(pA[2], pA[3]);
            ((unsigned*)&pfA)[2] = pack_bf2(pA[4], pA[5]);
            ((unsigned*)&pfA)[3] = pack_bf2(pA[6], pA[7]);
            ((unsigned*)&pfB)[0] = pack_bf2(pB[0], pB[1]);
            ((unsigned*)&pfB)[1] = pack_bf2(pB[2], pB[3]);
            ((unsigned*)&pfB)[2] = pack_bf2(pB[4], pB[5]);
            ((unsigned*)&pfB)[3] = pack_bf2(pB[6], pB[7]);

#pragma unroll
            for (int i = 0; i < 4; i++) {
                const int d = i * 16 + l15;
                const int x4 = (d & 30) * 4;
                const int bi = d * 128;
                const ushort4 v1 = *(const ushort4*)(Vs + bi + (((s * 8 + quad) * 4) ^ x4));
                const ushort4 v2 = *(const ushort4*)(Vs + bi + (((s * 8 + 4 + quad) * 4) ^ x4));
                bf16x8 vc;
                *(ushort4*)&vc = v1;
                *((ushort4*)&vc + 1) = v2;
                OA[i] = __builtin_amdgcn_mfma_f32_16x16x32_bf16(pfA, vc, OA[i], 0, 0, 0);
                OB[i] = __builtin_amdgcn_mfma_f32_16x16x32_bf16(pfB, vc, OB[i], 0, 0, 0);
            }
        }
    }

    // softmax denom: lane has partial for columns q0w+l15 (A) and q0w+16+l15 (B)
    rsA += __shfl_xor(rsA, 16); rsA += __shfl_xor(rsA, 32);
    rsB += __shfl_xor(rsB, 16); rsB += __shfl_xor(rsB, 32);
    float liA[4], liB[4];
#pragma unroll
    for (int r = 0; r < 4; r++) {
        liA[r] = 1.0f / __shfl(rsA, quad * 4 + r);
        liB[r] = 1.0f / __shfl(rsB, quad * 4 + r);
    }

    const int b = bh >> 4, h = bh & 15;
#pragma unroll
    for (int i = 0; i < 4; i++)
#pragma unroll
        for (int r = 0; r < 4; r++) {
            const int qa = q0w + quad * 4 + r;
            Oout[((size_t)b * Ll + qa) * Dd + h * DK + i * 16 + l15] = f2bf(OA[i][r] * liA[r]);
            Oout[((size_t)b * Ll + qa + 16) * Dd + h * DK + i * 16 + l15] = f2bf(OB[i][r] * liB[r]);
        }
}

// ---------------- output projection GEMM ----------------
__global__ __launch_bounds__(256) void gemm_o(const ushort* __restrict__ A,
                                              const ushort* __restrict__ W,
                                              const float* __restrict__ bias,
                                              float* __restrict__ Out) {
    __shared__ __align__(16) ushort As[64 * 32];
    __shared__ __align__(16) ushort Bs[128 * 32];
    const int t = threadIdx.x;
    const int wave = t >> 6, lane = t & 63;
    const int quad = lane >> 4, l15 = lane & 15;
    const int brow = blockIdx.y * 64, bcol = blockIdx.x * 128;
    const int wr = (wave >> 1) * 32, wc = (wave & 1) * 64;
    const int gr = wave * 16 + (lane >> 2);
    const int gc = (lane & 3) * 8;

    f32x4 acc[2][4] = {};

    for (int k0 = 0; k0 < Kk; k0 += 32) {
        __syncthreads();
        glds16(A + (size_t)(brow + gr) * Kk + k0 + gc,      As + wave * 512);
        glds16(W + (size_t)(bcol + gr) * Kk + k0 + gc,      Bs + wave * 512);
        glds16(W + (size_t)(bcol + 64 + gr) * Kk + k0 + gc, Bs + 2048 + wave * 512);
        __syncthreads();

        bf16x8 af[2], bfr[4];
#pragma unroll
        for (int i = 0; i < 2; i++)
            af[i] = *(const bf16x8*)(As + (wr + i * 16 + l15) * 32 + quad * 8);
#pragma unroll
        for (int j = 0; j < 4; j++)
            bfr[j] = *(const bf16x8*)(Bs + (wc + j * 16 + l15) * 32 + quad * 8);
#pragma unroll
        for (int i = 0; i < 2; i++)
#pragma unroll
            for (int j = 0; j < 4; j++)
                acc[i][j] = __builtin_amdgcn_mfma_f32_16x16x32_bf16(af[i], bfr[j], acc[i][j], 0, 0, 0);
    }

#pragma unroll
    for (int i = 0; i < 2; i++)
#pragma unroll
        for (int j = 0; j < 4; j++) {
            const int n = bcol + wc + j * 16 + l15;
            const float bv = bias[n];
#pragma unroll
            for (int r = 0; r < 4; r++) {
                const int m = brow + wr + i * 16 + quad * 4 + r;
                Out[(size_t)m * Nn + n] = acc[i][j][r] + bv;
            }
        }
}

// ---------------- launch ----------------
extern "C" void kernel_launch(void* const* d_in, const int* in_sizes, int n_in,
                              void* d_out, int out_size, void* d_ws, size_t ws_size,
                              hipStream_t stream) {
    const float* query = (const float*)d_in[0];
    const float* key   = (const float*)d_in[1];
    const float* value = (const float*)d_in[2];
    const float* Wq = (const float*)d_in[3];
    const float* bq = (const float*)d_in[4];
    const float* Wk = (const float*)d_in[5];
    const float* bk = (const float*)d_in[6];
    const float* Wv = (const float*)d_in[7];
    const float* bv = (const float*)d_in[8];
    const float* Wo = (const float*)d_in[9];
    const float* bo = (const float*)d_in[10];
    const int* masksize = (const int*)d_in[11];

    char* ws = (char*)d_ws;
    const size_t MB = 1024 * 1024;
    ushort* qb  = (ushort*)(ws + 0 * MB);
    ushort* kbf = (ushort*)(ws + 8 * MB);
    ushort* vbf = (ushort*)(ws + 16 * MB);
    ushort* wqb = (ushort*)(ws + 24 * MB);
    ushort* wkb = (ushort*)(ws + 26 * MB);
    ushort* wvb = (ushort*)(ws + 28 * MB);
    ushort* wob = (ushort*)(ws + 30 * MB);
    ushort* Qp  = (ushort*)(ws + 32 * MB);  // [BH, L, 64], pre-scaled by 0.125*log2e
    ushort* Kp  = (ushort*)(ws + 40 * MB);  // [BH, L, 64]
    ushort* Vt  = (ushort*)(ws + 48 * MB);  // [BH, 64, L]
    ushort* AO  = (ushort*)(ws + 56 * MB);  // [4096, 1024]

    cast_all<<<16384, 256, 0, stream>>>(query, key, value, Wq, Wk, Wv, Wo,
                                        qb, kbf, vbf, wqb, wkb, wvb, wob);

    gemm_qkv<<<dim3(8, 32, 3), 256, 0, stream>>>(qb, kbf, vbf,
                                                 wqb, wkb, wvb,
                                                 bq, bk, bv,
                                                 Qp, Kp, Vt);

    attn_kernel<<<1024, 128, 0, stream>>>(Qp, Kp, Vt, AO, masksize);

    gemm_o<<<dim3(8, 64), 256, 0, stream>>>(AO, wob, bo, (float*)d_out);
}

// Round 6
// 224.491 us; speedup vs baseline: 1.0431x; 1.0431x over previous
//
#include <hip/hip_runtime.h>
#include <hip/hip_bf16.h>

// Problem constants: B=2, L=2048, D=1024, H=16, d_k=64
#define Hh 16
#define Ll 2048
#define Dd 1024
#define DK 64
#define Mm 4096  // B*L
#define Kk 1024
#define Nn 1024

typedef short bf16x8 __attribute__((ext_vector_type(8)));
typedef float f32x4 __attribute__((ext_vector_type(4)));

static __device__ __forceinline__ unsigned short f2bf(float f) {
    union { __hip_bfloat16 b; unsigned short u; } cv;
    cv.b = __float2bfloat16(f);
    return cv.u;
}

// truncate-pack two fp32 -> bf16x2 (a in low half). Single v_perm_b32.
static __device__ __forceinline__ unsigned packtr(float a, float b) {
    return __builtin_amdgcn_perm(__builtin_bit_cast(unsigned, b),
                                 __builtin_bit_cast(unsigned, a), 0x07060302u);
}

static __device__ __forceinline__ float fexp2(float x) {
    return __builtin_amdgcn_exp2f(x);  // single v_exp_f32
}

// async global->LDS, 16B/lane. LDS dest = wave-uniform base + lane*16 (HW rule).
static __device__ __forceinline__ void glds16(const ushort* g, ushort* l) {
    __builtin_amdgcn_global_load_lds((const __attribute__((address_space(1))) unsigned int*)g,
                                     (__attribute__((address_space(3))) unsigned int*)l,
                                     16, 0, 0);
}

// ---------------- fused fp32 -> bf16 casts ----------------
__global__ __launch_bounds__(256) void cast_all(
    const float* __restrict__ q, const float* __restrict__ k, const float* __restrict__ v,
    const float* __restrict__ wq, const float* __restrict__ wk, const float* __restrict__ wv,
    const float* __restrict__ wo,
    ushort* __restrict__ qb, ushort* __restrict__ kb, ushort* __restrict__ vb,
    ushort* __restrict__ wqb, ushort* __restrict__ wkb, ushort* __restrict__ wvb,
    ushort* __restrict__ wob) {
    const int bx = blockIdx.x;
    const float4* s; ushort4* d; int base;
    if      (bx <  4096) { s = (const float4*)q;  d = (ushort4*)qb;  base = 0; }
    else if (bx <  8192) { s = (const float4*)k;  d = (ushort4*)kb;  base = 4096; }
    else if (bx < 12288) { s = (const float4*)v;  d = (ushort4*)vb;  base = 8192; }
    else if (bx < 13312) { s = (const float4*)wq; d = (ushort4*)wqb; base = 12288; }
    else if (bx < 14336) { s = (const float4*)wk; d = (ushort4*)wkb; base = 13312; }
    else if (bx < 15360) { s = (const float4*)wv; d = (ushort4*)wvb; base = 14336; }
    else                 { s = (const float4*)wo; d = (ushort4*)wob; base = 15360; }
    const int i = (bx - base) * 256 + threadIdx.x;
    float4 vv = s[i];
    ushort4 o;
    o.x = f2bf(vv.x); o.y = f2bf(vv.y); o.z = f2bf(vv.z); o.w = f2bf(vv.w);
    d[i] = o;
}

// ---------------- fused QKV projection GEMM ----------------
// C = A @ W^T + bias. z=0: Q, pre-scaled by 0.125*log2(e), scatter to [BH,L,64].
// z=1: K, scatter to [BH,L,64]. z=2: V, LDS-transposed epilogue -> [BH,64,L].
__global__ __launch_bounds__(256) void gemm_qkv(
    const ushort* __restrict__ A0, const ushort* __restrict__ A1, const ushort* __restrict__ A2,
    const ushort* __restrict__ W0, const ushort* __restrict__ W1, const ushort* __restrict__ W2,
    const float* __restrict__ b0, const float* __restrict__ b1, const float* __restrict__ b2,
    ushort* __restrict__ O0, ushort* __restrict__ O1, ushort* __restrict__ OVt) {
    __shared__ __align__(16) ushort SM[2 * 128 * 32];  // As | Bs ; reused as T in z==2 epilogue
    ushort* As = SM;
    ushort* Bs = SM + 4096;
    const int z = blockIdx.z;
    const ushort* A = (z == 0) ? A0 : (z == 1) ? A1 : A2;
    const ushort* W = (z == 0) ? W0 : (z == 1) ? W1 : W2;
    const float* bias = (z == 0) ? b0 : (z == 1) ? b1 : b2;

    const int t = threadIdx.x;
    const int wave = t >> 6, lane = t & 63;
    const int quad = lane >> 4, l15 = lane & 15;
    const int brow = blockIdx.y * 128, bcol = blockIdx.x * 128;
    const int wr = (wave >> 1) * 64, wc = (wave & 1) * 64;
    const int gr = wave * 16 + (lane >> 2);
    const int gc = (lane & 3) * 8;

    f32x4 acc[4][4] = {};

    for (int k0 = 0; k0 < Kk; k0 += 32) {
        __syncthreads();
        glds16(A + (size_t)(brow + gr) * Kk + k0 + gc,      As + wave * 512);
        glds16(A + (size_t)(brow + 64 + gr) * Kk + k0 + gc, As + 2048 + wave * 512);
        glds16(W + (size_t)(bcol + gr) * Kk + k0 + gc,      Bs + wave * 512);
        glds16(W + (size_t)(bcol + 64 + gr) * Kk + k0 + gc, Bs + 2048 + wave * 512);
        __syncthreads();

        bf16x8 af[4], bfr[4];
#pragma unroll
        for (int i = 0; i < 4; i++)
            af[i] = *(const bf16x8*)(As + (wr + i * 16 + l15) * 32 + quad * 8);
#pragma unroll
        for (int j = 0; j < 4; j++)
            bfr[j] = *(const bf16x8*)(Bs + (wc + j * 16 + l15) * 32 + quad * 8);
#pragma unroll
        for (int i = 0; i < 4; i++)
#pragma unroll
            for (int j = 0; j < 4; j++)
                acc[i][j] = __builtin_amdgcn_mfma_f32_16x16x32_bf16(af[i], bfr[j], acc[i][j], 0, 0, 0);
    }

    // C/D layout: row = quad*4+r, col = l15
    if (z < 2) {
        ushort* Out = (z == 0) ? O0 : O1;
        const float oscl = (z == 0) ? 0.18033688f : 1.0f;  // 0.125*log2(e) folded into Q
#pragma unroll
        for (int i = 0; i < 4; i++)
#pragma unroll
            for (int j = 0; j < 4; j++) {
                const int n = bcol + wc + j * 16 + l15;
                const float bv = bias[n];
                const int h = n >> 6, dk = n & 63;
#pragma unroll
                for (int r = 0; r < 4; r++) {
                    const int m = brow + wr + i * 16 + quad * 4 + r;
                    const int b = m >> 11, l = m & 2047;
                    Out[((size_t)(b * Hh + h) * Ll + l) * DK + dk] = f2bf((acc[i][j][r] + bv) * oscl);
                }
            }
    } else {
        // LDS transpose epilogue: emit V^T [BH, 64, L] with coalesced 16B stores.
        ushort* T = SM;  // T[32][136]
        const int b = brow >> 11;
        const int lbase = brow & 2047;
        const int npr = (wave & 1) * 16 + l15;
#pragma unroll
        for (int j = 0; j < 4; j++) {
            __syncthreads();
            const float bv = bias[bcol + wc + j * 16 + l15];
#pragma unroll
            for (int i = 0; i < 4; i++)
#pragma unroll
                for (int r = 0; r < 4; r++) {
                    const int m = wr + i * 16 + quad * 4 + r;
                    T[npr * 136 + m] = f2bf(acc[i][j][r] + bv);
                }
            __syncthreads();
#pragma unroll
            for (int cc = 0; cc < 2; cc++) {
                const int idx = t + cc * 256;
                const int ni = idx >> 4;
                const int ms = idx & 15;
                const int n = bcol + (ni >> 4) * 64 + j * 16 + (ni & 15);
                const int hh = n >> 6, dk = n & 63;
                uint4 val = *(const uint4*)(T + ni * 136 + ms * 8);
                *(uint4*)(OVt + ((size_t)(b * Hh + hh) * DK + dk) * Ll + lbase + ms * 8) = val;
            }
        }
    }
}

// ---------------- fused attention ----------------
// Block = 4 waves x 32 q = 128 q-rows, one head; 512 blocks = 2/CU.
// Waves 0-1 stage K (two d-panels [128][32]); waves 2-3 stage V ([64 d][swizzled keys]).
// Static-max softmax: mask const in MFMA acc init; exp2 -> truncate-pack (v_perm);
// row-sums via extra PV MFMA against a ones vector (no VALU adds, no end shuffles).
__global__ __launch_bounds__(256) void attn_kernel(const ushort* __restrict__ Q,
                                                   const ushort* __restrict__ Kp,
                                                   const ushort* __restrict__ Vt,
                                                   ushort* __restrict__ Oout,
                                                   const int* __restrict__ masksize) {
    __shared__ __align__(16) ushort Ks[2 * 128 * 32];  // 16KB
    __shared__ __align__(16) ushort Vs[64 * 128];      // 16KB
    const int t = threadIdx.x;
    const int wave = t >> 6, lane = t & 63;
    const int quad = lane >> 4, l15 = lane & 15;
    const int bx = blockIdx.x;
    const int bh = bx & 31, qc = bx >> 5;
    const int q0w = qc * 128 + wave * 32;    // this wave's 32 q-rows
    const int half = masksize[0] >> 1;
    const unsigned wid = (unsigned)(2 * half);

    const ushort* Qb = Q + (size_t)bh * (Ll * DK);
    const ushort* Kb = Kp + (size_t)bh * (Ll * DK);
    const ushort* Vb = Vt + (size_t)bh * (DK * Ll);

    // Q fragments (B-operand of S^T MFMA), two 16-q groups A/B
    const bf16x8 qA0 = *(const bf16x8*)(Qb + (size_t)(q0w + l15) * DK + quad * 8);
    const bf16x8 qA1 = *(const bf16x8*)(Qb + (size_t)(q0w + l15) * DK + 32 + quad * 8);
    const bf16x8 qB0 = *(const bf16x8*)(Qb + (size_t)(q0w + 16 + l15) * DK + quad * 8);
    const bf16x8 qB1 = *(const bf16x8*)(Qb + (size_t)(q0w + 16 + l15) * DK + 32 + quad * 8);

    const float C2IN  = (1.0f - 24.0f) * 1.44269504088896f;
    const float C2OUT = -24.0f * 1.44269504088896f;
    const float E1 = 2.718281828f;  // 2^(C2IN-C2OUT)

    bf16x8 onesf;
#pragma unroll
    for (int j = 0; j < 8; j++) onesf[j] = (short)0x3F80;  // bf16 1.0

    f32x4 OA[4] = {}, OB[4] = {};
    f32x4 SA = {}, SB = {};  // row-sum accumulators (value replicated across cols)

    // staging geometry
    const int krow = lane >> 2;              // key within 16-key chunk (waves 0-1)
    const int kcol8 = (lane & 3) * 8;        // d offset within 32-d panel
    const int vdl = lane >> 4;               // d within 4-row group (waves 2-3)
    const int vg0 = 2 * (lane & 15);         // LDS granule-pair base

    for (int kt = 0; kt < Ll; kt += 128) {
        __syncthreads();  // all waves done reading previous tile
        if (wave < 2) {
            const int cbase = wave * 4;
#pragma unroll
            for (int c = 0; c < 4; c++)
#pragma unroll
                for (int pan = 0; pan < 2; pan++)
                    glds16(Kb + (size_t)(kt + (cbase + c) * 16 + krow) * DK + pan * 32 + kcol8,
                           Ks + (pan * 128 + (cbase + c) * 16) * 32);
        } else {
            const int sb = (wave - 2) * 8;
#pragma unroll
            for (int i = 0; i < 8; i++) {
                const int sidx = sb + i;
                const int d = sidx * 4 + vdl;
                const int g0 = vg0 ^ (d & 30);
                glds16(Vb + (size_t)d * Ll + kt + g0 * 4, Vs + sidx * 512);
            }
        }
        __syncthreads();  // vmcnt(0) drain -> LDS ready

        // wave-uniform band-mask mode for this tile
        const int qlo = q0w, qhi = q0w + 31;
        const bool allout = (kt + 127 < qlo - half) || (kt > qhi + half);
        const bool allin  = (kt >= qhi - half) && (kt + 127 <= qlo + half);
        const bool uniform = allin || allout;
        const float cinit = allin ? C2IN : C2OUT;  // acc init (C2OUT for mixed)
        f32x4 cvec = {cinit, cinit, cinit, cinit};

#pragma unroll
        for (int s = 0; s < 4; s++) {
            const bf16x8 kf00 = *(const bf16x8*)(Ks + ((2 * s) * 16 + l15) * 32 + quad * 8);
            const bf16x8 kf01 = *(const bf16x8*)(Ks + 4096 + ((2 * s) * 16 + l15) * 32 + quad * 8);
            const bf16x8 kf10 = *(const bf16x8*)(Ks + ((2 * s + 1) * 16 + l15) * 32 + quad * 8);
            const bf16x8 kf11 = *(const bf16x8*)(Ks + 4096 + ((2 * s + 1) * 16 + l15) * 32 + quad * 8);
            f32x4 zA0 = __builtin_amdgcn_mfma_f32_16x16x32_bf16(kf00, qA0, cvec, 0, 0, 0);
            zA0 = __builtin_amdgcn_mfma_f32_16x16x32_bf16(kf01, qA1, zA0, 0, 0, 0);
            f32x4 zA1 = __builtin_amdgcn_mfma_f32_16x16x32_bf16(kf10, qA0, cvec, 0, 0, 0);
            zA1 = __builtin_amdgcn_mfma_f32_16x16x32_bf16(kf11, qA1, zA1, 0, 0, 0);
            f32x4 zB0 = __builtin_amdgcn_mfma_f32_16x16x32_bf16(kf00, qB0, cvec, 0, 0, 0);
            zB0 = __builtin_amdgcn_mfma_f32_16x16x32_bf16(kf01, qB1, zB0, 0, 0, 0);
            f32x4 zB1 = __builtin_amdgcn_mfma_f32_16x16x32_bf16(kf10, qB0, cvec, 0, 0, 0);
            zB1 = __builtin_amdgcn_mfma_f32_16x16x32_bf16(kf11, qB1, zB1, 0, 0, 0);

            float pA[8], pB[8];
            if (uniform) {
#pragma unroll
                for (int g = 0; g < 2; g++)
#pragma unroll
                    for (int r = 0; r < 4; r++) {
                        pA[g * 4 + r] = fexp2(g ? zA1[r] : zA0[r]);
                        pB[g * 4 + r] = fexp2(g ? zB1[r] : zB0[r]);
                    }
            } else {
                const int kb = kt + s * 32 + quad * 4 + half;
#pragma unroll
                for (int g = 0; g < 2; g++)
#pragma unroll
                    for (int r = 0; r < 4; r++) {
                        const unsigned ttA = (unsigned)(kb + g * 16 + r - (q0w + l15));
                        const unsigned ttB = (unsigned)(kb + g * 16 + r - (q0w + 16 + l15));
                        pA[g * 4 + r] = fexp2(g ? zA1[r] : zA0[r]) * (ttA <= wid ? E1 : 1.0f);
                        pB[g * 4 + r] = fexp2(g ? zB1[r] : zB0[r]) * (ttB <= wid ? E1 : 1.0f);
                    }
            }

            // truncate-pack to bf16 A-fragments (denominator uses same truncated values,
            // so softmax stays exactly normalized)
            bf16x8 pfA, pfB;
            ((unsigned*)&pfA)[0] = packtr(pA[0], pA[1]);
            ((unsigned*)&pfA)[1] = packtr(pA[2], pA[3]);
            ((unsigned*)&pfA)[2] = packtr(pA[4], pA[5]);
            ((unsigned*)&pfA)[3] = packtr(pA[6], pA[7]);
            ((unsigned*)&pfB)[0] = packtr(pB[0], pB[1]);
            ((unsigned*)&pfB)[1] = packtr(pB[2], pB[3]);
            ((unsigned*)&pfB)[2] = packtr(pB[4], pB[5]);
            ((unsigned*)&pfB)[3] = packtr(pB[6], pB[7]);

            // row-sums via MFMA against ones (replaces 28 VALU adds)
            SA = __builtin_amdgcn_mfma_f32_16x16x32_bf16(pfA, onesf, SA, 0, 0, 0);
            SB = __builtin_amdgcn_mfma_f32_16x16x32_bf16(pfB, onesf, SB, 0, 0, 0);

#pragma unroll
            for (int i = 0; i < 4; i++) {
                const int d = i * 16 + l15;
                const int x4 = (d & 30) * 4;
                const int bi = d * 128;
                const ushort4 v1 = *(const ushort4*)(Vs + bi + (((s * 8 + quad) * 4) ^ x4));
                const ushort4 v2 = *(const ushort4*)(Vs + bi + (((s * 8 + 4 + quad) * 4) ^ x4));
                bf16x8 vc;
                *(ushort4*)&vc = v1;
                *((ushort4*)&vc + 1) = v2;
                OA[i] = __builtin_amdgcn_mfma_f32_16x16x32_bf16(pfA, vc, OA[i], 0, 0, 0);
                OB[i] = __builtin_amdgcn_mfma_f32_16x16x32_bf16(pfB, vc, OB[i], 0, 0, 0);
            }
        }
    }

    // normalize: SA/SB hold row-sums (same value in every column register)
    float liA[4], liB[4];
#pragma unroll
    for (int r = 0; r < 4; r++) {
        liA[r] = 1.0f / SA[r];
        liB[r] = 1.0f / SB[r];
    }

    const int b = bh >> 4, h = bh & 15;
#pragma unroll
    for (int i = 0; i < 4; i++)
#pragma unroll
        for (int r = 0; r < 4; r++) {
            const int qa = q0w + quad * 4 + r;
            Oout[((size_t)b * Ll + qa) * Dd + h * DK + i * 16 + l15] = f2bf(OA[i][r] * liA[r]);
            Oout[((size_t)b * Ll + qa + 16) * Dd + h * DK + i * 16 + l15] = f2bf(OB[i][r] * liB[r]);
        }
}

// ---------------- output projection GEMM ----------------
__global__ __launch_bounds__(256) void gemm_o(const ushort* __restrict__ A,
                                              const ushort* __restrict__ W,
                                              const float* __restrict__ bias,
                                              float* __restrict__ Out) {
    __shared__ __align__(16) ushort As[64 * 32];
    __shared__ __align__(16) ushort Bs[128 * 32];
    const int t = threadIdx.x;
    const int wave = t >> 6, lane = t & 63;
    const int quad = lane >> 4, l15 = lane & 15;
    const int brow = blockIdx.y * 64, bcol = blockIdx.x * 128;
    const int wr = (wave >> 1) * 32, wc = (wave & 1) * 64;
    const int gr = wave * 16 + (lane >> 2);
    const int gc = (lane & 3) * 8;

    f32x4 acc[2][4] = {};

    for (int k0 = 0; k0 < Kk; k0 += 32) {
        __syncthreads();
        glds16(A + (size_t)(brow + gr) * Kk + k0 + gc,      As + wave * 512);
        glds16(W + (size_t)(bcol + gr) * Kk + k0 + gc,      Bs + wave * 512);
        glds16(W + (size_t)(bcol + 64 + gr) * Kk + k0 + gc, Bs + 2048 + wave * 512);
        __syncthreads();

        bf16x8 af[2], bfr[4];
#pragma unroll
        for (int i = 0; i < 2; i++)
            af[i] = *(const bf16x8*)(As + (wr + i * 16 + l15) * 32 + quad * 8);
#pragma unroll
        for (int j = 0; j < 4; j++)
            bfr[j] = *(const bf16x8*)(Bs + (wc + j * 16 + l15) * 32 + quad * 8);
#pragma unroll
        for (int i = 0; i < 2; i++)
#pragma unroll
            for (int j = 0; j < 4; j++)
                acc[i][j] = __builtin_amdgcn_mfma_f32_16x16x32_bf16(af[i], bfr[j], acc[i][j], 0, 0, 0);
    }

#pragma unroll
    for (int i = 0; i < 2; i++)
#pragma unroll
        for (int j = 0; j < 4; j++) {
            const int n = bcol + wc + j * 16 + l15;
            const float bv = bias[n];
#pragma unroll
            for (int r = 0; r < 4; r++) {
                const int m = brow + wr + i * 16 + quad * 4 + r;
                Out[(size_t)m * Nn + n] = acc[i][j][r] + bv;
            }
        }
}

// ---------------- launch ----------------
extern "C" void kernel_launch(void* const* d_in, const int* in_sizes, int n_in,
                              void* d_out, int out_size, void* d_ws, size_t ws_size,
                              hipStream_t stream) {
    const float* query = (const float*)d_in[0];
    const float* key   = (const float*)d_in[1];
    const float* value = (const float*)d_in[2];
    const float* Wq = (const float*)d_in[3];
    const float* bq = (const float*)d_in[4];
    const float* Wk = (const float*)d_in[5];
    const float* bk = (const float*)d_in[6];
    const float* Wv = (const float*)d_in[7];
    const float* bv = (const float*)d_in[8];
    const float* Wo = (const float*)d_in[9];
    const float* bo = (const float*)d_in[10];
    const int* masksize = (const int*)d_in[11];

    char* ws = (char*)d_ws;
    const size_t MB = 1024 * 1024;
    ushort* qb  = (ushort*)(ws + 0 * MB);
    ushort* kbf = (ushort*)(ws + 8 * MB);
    ushort* vbf = (ushort*)(ws + 16 * MB);
    ushort* wqb = (ushort*)(ws + 24 * MB);
    ushort* wkb = (ushort*)(ws + 26 * MB);
    ushort* wvb = (ushort*)(ws + 28 * MB);
    ushort* wob = (ushort*)(ws + 30 * MB);
    ushort* Qp  = (ushort*)(ws + 32 * MB);  // [BH, L, 64], pre-scaled by 0.125*log2e
    ushort* Kp  = (ushort*)(ws + 40 * MB);  // [BH, L, 64]
    ushort* Vt  = (ushort*)(ws + 48 * MB);  // [BH, 64, L]
    ushort* AO  = (ushort*)(ws + 56 * MB);  // [4096, 1024]

    cast_all<<<16384, 256, 0, stream>>>(query, key, value, Wq, Wk, Wv, Wo,
                                        qb, kbf, vbf, wqb, wkb, wvb, wob);

    gemm_qkv<<<dim3(8, 32, 3), 256, 0, stream>>>(qb, kbf, vbf,
                                                 wqb, wkb, wvb,
                                                 bq, bk, bv,
                                                 Qp, Kp, Vt);

    attn_kernel<<<512, 256, 0, stream>>>(Qp, Kp, Vt, AO, masksize);

    gemm_o<<<dim3(8, 64), 256, 0, stream>>>(AO, wob, bo, (float*)d_out);
}